// Round 8
// baseline (249.956 us; speedup 1.0000x reference)
//
#include <hip/hip_runtime.h>
#include <hip/hip_fp16.h>

#define TT 256
#define PP 88
#define CC 128
#define NN (TT * PP)          // 22528 positions
#define NPAD (NN + 32)
#define HEADS 4
#define HD 32
#define WIN 25
#define RPBW 49
#define RPBSZ (RPBW * RPBW)   // 2401
#define SCALE 0.17677669529663687f   // 1/sqrt(32)
#define LOG2E 1.4426950408889634f
#define QSC (SCALE * LOG2E)          // fold exp->exp2 into Q path

#if __has_builtin(__builtin_amdgcn_exp2f)
#define EXP2(x) __builtin_amdgcn_exp2f(x)
#else
#define EXP2(x) exp2f(x)
#endif

typedef _Float16 f16;
typedef f16 f16x8 __attribute__((ext_vector_type(8)));
typedef f16 f16x8u __attribute__((ext_vector_type(8), aligned(4)));
typedef float f32x4 __attribute__((ext_vector_type(4)));
typedef float f32x4u __attribute__((ext_vector_type(4), aligned(4)));
typedef __fp16 hf16x2 __attribute__((ext_vector_type(2)));
union PkU { hf16x2 h; unsigned u; };

// ---------- prep: weight/bias/rpb repack (blocks 0-191) + combined layer-2 W (192-383) ----------
__global__ void prep(const float* __restrict__ lw, const float* __restrict__ qw,
                     const float* __restrict__ pw, const float* __restrict__ qb,
                     const float* __restrict__ pb, const float* __restrict__ rpb,
                     f16* __restrict__ lwh, f16* __restrict__ qwh, f16* __restrict__ pwh,
                     f16* __restrict__ w2h, float* __restrict__ qbs, float* __restrict__ b2s,
                     float* __restrict__ rpbp) {
    if (blockIdx.x < 192) {
        int idx = blockIdx.x * 256 + threadIdx.x;     // covers 49152
        if (idx < 128 * 160) {                        // fusion W: [128][131] -> [128][160] pad
            int r = idx / 160, c = idx - r * 160;
            lwh[idx] = (f16)(c < 131 ? lw[r * 131 + c] : 0.f);
        }
        if (idx < 384 * 128) {                        // qkv W, Q rows scaled by QSC
            float v = qw[idx];
            if (idx < 128 * 128) v *= QSC;
            qwh[idx] = (f16)v;
        }
        if (idx < 128 * 128) pwh[idx] = (f16)pw[idx];
        if (idx < 384) qbs[idx] = qb[idx] * (idx < 128 ? QSC : 1.f);
        if (idx < 10240) rpbp[idx] = (idx < 4 * RPBSZ) ? rpb[idx] * LOG2E : 0.f;
    } else {
        int idx = (blockIdx.x - 192) * 256 + threadIdx.x;   // 49152: W2 = qw @ pw
        int i = idx >> 7, k = idx & 127;
        float acc = 0.f;
        for (int j = 0; j < 128; j++) acc += qw[i * 128 + j] * pw[j * 128 + k];
        if (i < 128) acc *= QSC;
        w2h[idx] = (f16)acc;
        if (idx < 384) {
            float b = qb[idx];
            for (int j = 0; j < 128; j++) b += qw[idx * 128 + j] * pb[j];
            b2s[idx] = b * (idx < 128 ? QSC : 1.f);
        }
    }
}

// ---------- fused input stage: cat -> y (LDS only) -> Q|K / V^T ----------
__global__ __launch_bounds__(256) void fused_in(
    const float* __restrict__ x, const float* __restrict__ cond, const float* __restrict__ mask,
    const f16* __restrict__ lwh, const float* __restrict__ lb,
    const f16* __restrict__ qwh, const float* __restrict__ qbs,
    f16* __restrict__ qkh, f16* __restrict__ vt)
{
    __shared__ __align__(16) f16 Alds[64 * 168];
    __shared__ __align__(16) f16 Ylds[64 * 136];
    const int m0 = blockIdx.x * 64;
    const int tid = threadIdx.x;
    const int w = tid >> 6, lane = tid & 63, quad = lane >> 4, nn = lane & 15;

    {   // stage cat rows (f16)
        int r = tid >> 2, cpart = tid & 3;
        size_t pos = m0 + r;
        *(uint4*)&Alds[r * 168 + 128 + cpart * 8] = make_uint4(0, 0, 0, 0);
        const float* xr = x + pos * 128 + cpart * 32;
        #pragma unroll
        for (int t = 0; t < 4; t++) {
            float4 a = *(const float4*)(xr + t * 8);
            float4 b = *(const float4*)(xr + t * 8 + 4);
            PkU p0, p1, p2, p3;
            p0.h = __builtin_amdgcn_cvt_pkrtz(a.x, a.y);
            p1.h = __builtin_amdgcn_cvt_pkrtz(a.z, a.w);
            p2.h = __builtin_amdgcn_cvt_pkrtz(b.x, b.y);
            p3.h = __builtin_amdgcn_cvt_pkrtz(b.z, b.w);
            *(uint4*)&Alds[r * 168 + cpart * 32 + t * 8] = make_uint4(p0.u, p1.u, p2.u, p3.u);
        }
        if (cpart == 0) {
            Alds[r * 168 + 128] = (f16)cond[pos * 2];
            Alds[r * 168 + 129] = (f16)cond[pos * 2 + 1];
            Alds[r * 168 + 130] = (f16)mask[pos];
        }
    }
    __syncthreads();

    // y = relu(cat @ lwh^T + lb), kept in LDS (C-layout: lane nn = position, regs = outcols)
    #pragma unroll
    for (int t = 0; t < 2; t++) {
        const int n0 = t * 64;
        const int oc = n0 + w * 16 + nn;
        f16x8 af[5];
        #pragma unroll
        for (int ks = 0; ks < 5; ks++)
            af[ks] = *(const f16x8*)&lwh[(size_t)oc * 160 + ks * 32 + quad * 8];
        f32x4 acc[4] = {};
        #pragma unroll
        for (int ks = 0; ks < 5; ks++)
            #pragma unroll
            for (int nt = 0; nt < 4; nt++) {
                f16x8 bf = *(const f16x8*)&Alds[(nt * 16 + nn) * 168 + ks * 32 + quad * 8];
                acc[nt] = __builtin_amdgcn_mfma_f32_16x16x32_f16(af[ks], bf, acc[nt], 0, 0, 0);
            }
        float bv[4];
        #pragma unroll
        for (int r = 0; r < 4; r++) bv[r] = lb[n0 + w * 16 + quad * 4 + r];
        #pragma unroll
        for (int nt = 0; nt < 4; nt++) {
            PkU p0, p1;
            p0.h = __builtin_amdgcn_cvt_pkrtz(fmaxf(acc[nt][0] + bv[0], 0.f), fmaxf(acc[nt][1] + bv[1], 0.f));
            p1.h = __builtin_amdgcn_cvt_pkrtz(fmaxf(acc[nt][2] + bv[2], 0.f), fmaxf(acc[nt][3] + bv[3], 0.f));
            *(uint2*)&Ylds[(nt * 16 + nn) * 136 + n0 + w * 16 + quad * 4] = make_uint2(p0.u, p1.u);
        }
    }
    __syncthreads();

    // qkv = y @ qwh^T + qbs; direct stores (Q|K rows stride 256; V transposed)
    #pragma unroll
    for (int u = 0; u < 6; u++) {
        const int n0 = u * 64;
        const int oc = n0 + w * 16 + nn;
        f16x8 af[4];
        #pragma unroll
        for (int ks = 0; ks < 4; ks++)
            af[ks] = *(const f16x8*)&qwh[(size_t)oc * 128 + ks * 32 + quad * 8];
        f32x4 acc[4] = {};
        #pragma unroll
        for (int ks = 0; ks < 4; ks++)
            #pragma unroll
            for (int nt = 0; nt < 4; nt++) {
                f16x8 bf = *(const f16x8*)&Ylds[(nt * 16 + nn) * 136 + ks * 32 + quad * 8];
                acc[nt] = __builtin_amdgcn_mfma_f32_16x16x32_f16(af[ks], bf, acc[nt], 0, 0, 0);
            }
        float bv[4];
        #pragma unroll
        for (int r = 0; r < 4; r++) bv[r] = qbs[n0 + w * 16 + quad * 4 + r];
        if (n0 < 256) {
            #pragma unroll
            for (int nt = 0; nt < 4; nt++) {
                int pos = m0 + nt * 16 + nn;
                PkU p0, p1;
                p0.h = __builtin_amdgcn_cvt_pkrtz(acc[nt][0] + bv[0], acc[nt][1] + bv[1]);
                p1.h = __builtin_amdgcn_cvt_pkrtz(acc[nt][2] + bv[2], acc[nt][3] + bv[3]);
                *(uint2*)&qkh[(size_t)pos * 256 + n0 + w * 16 + quad * 4] = make_uint2(p0.u, p1.u);
            }
        } else {
            #pragma unroll
            for (int nt = 0; nt < 4; nt++) {
                int pos = m0 + nt * 16 + nn;
                #pragma unroll
                for (int r = 0; r < 4; r++) {
                    int chg = n0 - 256 + w * 16 + quad * 4 + r;
                    vt[(size_t)chg * NPAD + pos] = (f16)(acc[nt][r] + bv[r]);
                }
            }
        }
    }
}

// ---------- layer-2 fused proj+qkv GEMM: ao @ w2h^T + b2s -> Q|K / V^T ----------
__global__ __launch_bounds__(256) void gemm_qkv2(
    const f16* __restrict__ A, const f16* __restrict__ W, const float* __restrict__ bias,
    f16* __restrict__ qkh, f16* __restrict__ vt)
{
    __shared__ __align__(16) f16 Alds[64 * 136];
    const int m0 = blockIdx.x * 64;
    const int tid = threadIdx.x;
    const int w = tid >> 6, lane = tid & 63, quad = lane >> 4, nn = lane & 15;

    for (int i = tid; i < 1024; i += 256) {
        int r = i >> 4, c = i & 15;
        *(uint4*)&Alds[r * 136 + c * 8] = *(const uint4*)&A[(size_t)(m0 + r) * 128 + c * 8];
    }
    __syncthreads();

    #pragma unroll
    for (int u = 0; u < 6; u++) {
        const int n0 = u * 64;
        const int oc = n0 + w * 16 + nn;
        f16x8 af[4];
        #pragma unroll
        for (int ks = 0; ks < 4; ks++)
            af[ks] = *(const f16x8*)&W[(size_t)oc * 128 + ks * 32 + quad * 8];
        f32x4 acc[4] = {};
        #pragma unroll
        for (int ks = 0; ks < 4; ks++)
            #pragma unroll
            for (int nt = 0; nt < 4; nt++) {
                f16x8 bf = *(const f16x8*)&Alds[(nt * 16 + nn) * 136 + ks * 32 + quad * 8];
                acc[nt] = __builtin_amdgcn_mfma_f32_16x16x32_f16(af[ks], bf, acc[nt], 0, 0, 0);
            }
        float bv[4];
        #pragma unroll
        for (int r = 0; r < 4; r++) bv[r] = bias[n0 + w * 16 + quad * 4 + r];
        if (n0 < 256) {
            #pragma unroll
            for (int nt = 0; nt < 4; nt++) {
                int pos = m0 + nt * 16 + nn;
                PkU p0, p1;
                p0.h = __builtin_amdgcn_cvt_pkrtz(acc[nt][0] + bv[0], acc[nt][1] + bv[1]);
                p1.h = __builtin_amdgcn_cvt_pkrtz(acc[nt][2] + bv[2], acc[nt][3] + bv[3]);
                *(uint2*)&qkh[(size_t)pos * 256 + n0 + w * 16 + quad * 4] = make_uint2(p0.u, p1.u);
            }
        } else {
            #pragma unroll
            for (int nt = 0; nt < 4; nt++) {
                int pos = m0 + nt * 16 + nn;
                #pragma unroll
                for (int r = 0; r < 4; r++) {
                    int chg = n0 - 256 + w * 16 + quad * 4 + r;
                    vt[(size_t)chg * NPAD + pos] = (f16)(acc[nt][r] + bv[r]);
                }
            }
        }
    }
}

// ---------- final projection: ao @ pwh^T + pb -> fp32 out ----------
__global__ __launch_bounds__(256) void gemm_out(
    const f16* __restrict__ A, const f16* __restrict__ W, const float* __restrict__ bias,
    float* __restrict__ outp)
{
    __shared__ __align__(16) f16 Alds[64 * 136];
    const int m0 = blockIdx.x * 64;
    const int tid = threadIdx.x;
    const int w = tid >> 6, lane = tid & 63, quad = lane >> 4, nn = lane & 15;

    for (int i = tid; i < 1024; i += 256) {
        int r = i >> 4, c = i & 15;
        *(uint4*)&Alds[r * 136 + c * 8] = *(const uint4*)&A[(size_t)(m0 + r) * 128 + c * 8];
    }
    __syncthreads();

    #pragma unroll
    for (int u = 0; u < 2; u++) {
        const int n0 = u * 64;
        const int oc = n0 + w * 16 + nn;
        f16x8 af[4];
        #pragma unroll
        for (int ks = 0; ks < 4; ks++)
            af[ks] = *(const f16x8*)&W[(size_t)oc * 128 + ks * 32 + quad * 8];
        f32x4 acc[4] = {};
        #pragma unroll
        for (int ks = 0; ks < 4; ks++)
            #pragma unroll
            for (int nt = 0; nt < 4; nt++) {
                f16x8 bf = *(const f16x8*)&Alds[(nt * 16 + nn) * 136 + ks * 32 + quad * 8];
                acc[nt] = __builtin_amdgcn_mfma_f32_16x16x32_f16(af[ks], bf, acc[nt], 0, 0, 0);
            }
        float bv[4];
        #pragma unroll
        for (int r = 0; r < 4; r++) bv[r] = bias[n0 + w * 16 + quad * 4 + r];
        #pragma unroll
        for (int nt = 0; nt < 4; nt++) {
            int pos = m0 + nt * 16 + nn;
            f32x4 vv;
            #pragma unroll
            for (int r = 0; r < 4; r++) vv[r] = acc[nt][r] + bv[r];
            *(f32x4*)&outp[(size_t)pos * 128 + n0 + w * 16 + quad * 4] = vv;
        }
    }
}

// ---------- MFMA neighborhood attention: 8x8 query tile, 4 waves key-split ----------
// rpb+mask folded into S-MFMA accumulator (exp2 domain); l accumulated by a 5th MFMA
// (reg-layout = queries, matches O) -> no VALU sum chain, no epilogue shuffles.
// Wave w handles key rows [w*8, w*8+8); tree-merge via LDS. OOB addrs clamped+masked.
__global__ __launch_bounds__(256) void attn_mfma(
    const f16* __restrict__ qkh,   // [N][256] = Q|K, Q pre-scaled by QSC
    const f16* __restrict__ vt,    // [128][NPAD]
    const float* __restrict__ rpbp,
    f16* __restrict__ ao)          // [N][128]
{
    const int i0 = blockIdx.x * 8;
    const int j0 = blockIdx.y * 8;
    const int h  = blockIdx.z;
    const int tid = threadIdx.x;
    const int w = tid >> 6, lane = tid & 63;
    const int quad = lane >> 4, nn = lane & 15;

    const int ri0 = min(max(i0 - 12, 0), TT - 32);
    const int rj0 = min(max(j0 - 12, 0), PP - WIN) & ~1;

    __shared__ f16 Plds[4][16][36];
    __shared__ __align__(16) float Olds[2][64][48];

    int qi_[4], si_[4], dbb_[4];
    unsigned cm_[4];
    f16x8 qf[4];
    #pragma unroll
    for (int qs = 0; qs < 4; qs++) {
        int ql = qs * 16 + nn;
        int qi = i0 + (ql >> 3), qj = j0 + (ql & 7);
        int si = min(max(qi - 12, 0), TT - WIN);
        int sj = min(max(qj - 12, 0), PP - WIN);
        qi_[qs] = qi; si_[qs] = si;
        cm_[qs] = 0x1FFFFFFu << (sj - rj0);       // shift <= 7
        dbb_[qs] = rj0 - qj + 24;
        qf[qs] = *(const f16x8*)&qkh[(size_t)(qi * PP + qj) * 256 + h * HD + quad * 8];
    }
    const float* rp_h = rpbp + h * RPBSZ;
    const f16* vbase = vt + (size_t)(h * HD + nn) * NPAD;
    const f16x8 onesv = {(f16)1.f, (f16)1.f, (f16)1.f, (f16)1.f,
                         (f16)1.f, (f16)1.f, (f16)1.f, (f16)1.f};

    f32x4 O[4][2] = {};    // [qset][ch-half]; regs = queries, lane nn = channel
    f32x4 lacc[4] = {};    // regs = queries

    for (int c = w * 8; c < w * 8 + 8; c++) {
        int aa = ri0 + c;                                   // in [0,255]
        const f16* rowK = qkh + (size_t)aa * PP * 256 + 128 + h * HD + quad * 8;
        int b0 = min(rj0 + nn, PP - 1);
        int b1 = min(rj0 + 16 + nn, PP - 1);
        f16x8 kf0 = *(const f16x8*)(rowK + (size_t)b0 * 256);
        f16x8 kf1 = *(const f16x8*)(rowK + (size_t)b1 * 256);
        const f16* vrow = vbase + aa * PP + rj0 + quad * 8;
        f16x8 vf0 = *(const f16x8u*)vrow;
        f16x8 vf1 = *(const f16x8u*)(vrow + (size_t)16 * NPAD);

        #pragma unroll
        for (int qs = 0; qs < 4; qs++) {
            bool row_ok = (unsigned)(aa - si_[qs]) <= 24u;
            if (__ballot(row_ok) == 0ULL) continue;         // wave-uniform skip
            unsigned vm = row_ok ? cm_[qs] : 0u;
            const float* rp = rp_h + (aa - qi_[qs] + 24) * RPBW + dbb_[qs];
            f32x4 ra = *(const f32x4u*)(rp + quad * 4);
            f32x4 rb = *(const f32x4u*)(rp + 16 + quad * 4);
            f32x4 za, zb;
            #pragma unroll
            for (int r = 0; r < 4; r++) {
                int kl0 = quad * 4 + r;
                za[r] = ((vm >> kl0) & 1u) ? ra[r] : -1e30f;
                zb[r] = ((vm >> (kl0 + 16)) & 1u) ? rb[r] : -1e30f;
            }
            f32x4 s0 = __builtin_amdgcn_mfma_f32_16x16x32_f16(kf0, qf[qs], za, 0, 0, 0);
            f32x4 s1 = __builtin_amdgcn_mfma_f32_16x16x32_f16(kf1, qf[qs], zb, 0, 0, 0);

            float p[8];
            #pragma unroll
            for (int r = 0; r < 4; r++) {
                p[r]     = EXP2(s0[r]);
                p[r + 4] = EXP2(s1[r]);
            }
            PkU a, b, cc, d;
            a.h  = __builtin_amdgcn_cvt_pkrtz(p[0], p[1]);
            b.h  = __builtin_amdgcn_cvt_pkrtz(p[2], p[3]);
            cc.h = __builtin_amdgcn_cvt_pkrtz(p[4], p[5]);
            d.h  = __builtin_amdgcn_cvt_pkrtz(p[6], p[7]);
            *(unsigned*)&Plds[w][nn][quad * 4]          = a.u;
            *(unsigned*)&Plds[w][nn][quad * 4 + 2]      = b.u;
            *(unsigned*)&Plds[w][nn][16 + quad * 4]     = cc.u;
            *(unsigned*)&Plds[w][nn][16 + quad * 4 + 2] = d.u;
            f16x8 pf = *(const f16x8*)&Plds[w][nn][quad * 8];

            O[qs][0] = __builtin_amdgcn_mfma_f32_16x16x32_f16(pf, vf0, O[qs][0], 0, 0, 0);
            O[qs][1] = __builtin_amdgcn_mfma_f32_16x16x32_f16(pf, vf1, O[qs][1], 0, 0, 0);
            lacc[qs] = __builtin_amdgcn_mfma_f32_16x16x32_f16(pf, onesv, lacc[qs], 0, 0, 0);
        }
    }

    // ---- tree merge: (w2,w3) -> (w0,w1), then w1 -> w0 ----
    if (w >= 2) {
        float* ob = Olds[w - 2][lane];
        #pragma unroll
        for (int qs = 0; qs < 4; qs++) {
            *(f32x4*)&ob[qs * 12]     = O[qs][0];
            *(f32x4*)&ob[qs * 12 + 4] = O[qs][1];
            *(f32x4*)&ob[qs * 12 + 8] = lacc[qs];
        }
    }
    __syncthreads();
    if (w < 2) {
        const float* ob = Olds[w][lane];
        #pragma unroll
        for (int qs = 0; qs < 4; qs++) {
            O[qs][0] += *(const f32x4*)&ob[qs * 12];
            O[qs][1] += *(const f32x4*)&ob[qs * 12 + 4];
            lacc[qs] += *(const f32x4*)&ob[qs * 12 + 8];
        }
    }
    __syncthreads();
    if (w == 1) {
        float* ob = Olds[0][lane];
        #pragma unroll
        for (int qs = 0; qs < 4; qs++) {
            *(f32x4*)&ob[qs * 12]     = O[qs][0];
            *(f32x4*)&ob[qs * 12 + 4] = O[qs][1];
            *(f32x4*)&ob[qs * 12 + 8] = lacc[qs];
        }
    }
    __syncthreads();
    if (w == 0) {
        const float* ob = Olds[0][lane];
        #pragma unroll
        for (int qs = 0; qs < 4; qs++) {
            O[qs][0] += *(const f32x4*)&ob[qs * 12];
            O[qs][1] += *(const f32x4*)&ob[qs * 12 + 4];
            lacc[qs] += *(const f32x4*)&ob[qs * 12 + 8];
            #pragma unroll
            for (int r = 0; r < 4; r++) {
                float li = 1.f / lacc[qs][r];
                int ql = qs * 16 + quad * 4 + r;
                int qi = i0 + (ql >> 3), qj = j0 + (ql & 7);
                size_t base = (size_t)(qi * PP + qj) * CC + h * HD;
                ao[base + nn]      = (f16)(O[qs][0][r] * li);
                ao[base + 16 + nn] = (f16)(O[qs][1][r] * li);
            }
        }
    }
}

extern "C" void kernel_launch(void* const* d_in, const int* in_sizes, int n_in,
                              void* d_out, int out_size, void* d_ws, size_t ws_size,
                              hipStream_t stream) {
    (void)in_sizes; (void)n_in; (void)out_size; (void)ws_size;
    const float* x    = (const float*)d_in[0];
    const float* cond = (const float*)d_in[1];
    const float* mask = (const float*)d_in[2];
    const float* lw   = (const float*)d_in[3];
    const float* lb   = (const float*)d_in[4];
    const float* qw   = (const float*)d_in[5];
    const float* qb   = (const float*)d_in[6];
    const float* rpb  = (const float*)d_in[7];
    const float* pw   = (const float*)d_in[8];
    const float* pb   = (const float*)d_in[9];
    float* outp       = (float*)d_out;

    float* ws   = (float*)d_ws;
    float* qbs  = ws;                 // 384
    float* b2s  = qbs + 384;          // 384
    float* rpbp = b2s + 384;          // 10240 padded
    f16* lwh  = (f16*)(rpbp + 10240);             // 128*160
    f16* qwh  = lwh + 20480;                      // 384*128
    f16* pwh  = qwh + 49152;                      // 128*128
    f16* w2h  = pwh + 16384;                      // 384*128
    f16* qkh  = w2h + 49152;                      // NN*256 (Q|K)
    f16* vt   = qkh + (size_t)NN * 256;           // 128*NPAD
    f16* ao   = vt + (size_t)128 * NPAD;          // NN*128

    prep<<<384, 256, 0, stream>>>(lw, qw, pw, qb, pb, rpb, lwh, qwh, pwh, w2h, qbs, b2s, rpbp);
    fused_in<<<352, 256, 0, stream>>>(x, cond, mask, lwh, lb, qwh, qbs, qkh, vt);
    attn_mfma<<<dim3(TT / 8, PP / 8, HEADS), 256, 0, stream>>>(qkh, vt, rpbp, ao);
    gemm_qkv2<<<352, 256, 0, stream>>>(ao, w2h, b2s, qkh, vt);
    attn_mfma<<<dim3(TT / 8, PP / 8, HEADS), 256, 0, stream>>>(qkh, vt, rpbp, ao);
    gemm_out<<<352, 256, 0, stream>>>(ao, pwh, pb, outp);
}

// Round 9
// 221.251 us; speedup vs baseline: 1.1297x; 1.1297x over previous
//
#include <hip/hip_runtime.h>
#include <hip/hip_fp16.h>

#define TT 256
#define PP 88
#define CC 128
#define NN (TT * PP)          // 22528 positions
#define NPAD (NN + 32)
#define HEADS 4
#define HD 32
#define WIN 25
#define RPBW 49
#define RPBSZ (RPBW * RPBW)   // 2401
#define SCALE 0.17677669529663687f   // 1/sqrt(32)
#define LOG2E 1.4426950408889634f
#define QSC (SCALE * LOG2E)          // fold exp->exp2 into Q path

#if __has_builtin(__builtin_amdgcn_exp2f)
#define EXP2(x) __builtin_amdgcn_exp2f(x)
#else
#define EXP2(x) exp2f(x)
#endif

typedef _Float16 f16;
typedef f16 f16x8 __attribute__((ext_vector_type(8)));
typedef f16 f16x8u __attribute__((ext_vector_type(8), aligned(4)));
typedef float f32x4 __attribute__((ext_vector_type(4)));
typedef float f32x4u __attribute__((ext_vector_type(4), aligned(4)));
typedef __fp16 hf16x2 __attribute__((ext_vector_type(2)));
union PkU { hf16x2 h; unsigned u; };

// ---------- prep: weight/bias/rpb repack (blocks 0-191) + combined layer-2 W (192-383) ----------
__global__ void prep(const float* __restrict__ lw, const float* __restrict__ qw,
                     const float* __restrict__ pw, const float* __restrict__ qb,
                     const float* __restrict__ pb, const float* __restrict__ rpb,
                     f16* __restrict__ lwh, f16* __restrict__ qwh, f16* __restrict__ pwh,
                     f16* __restrict__ w2h, float* __restrict__ qbs, float* __restrict__ b2s,
                     float* __restrict__ rpbp) {
    if (blockIdx.x < 192) {
        int idx = blockIdx.x * 256 + threadIdx.x;     // covers 49152
        if (idx < 128 * 160) {                        // fusion W: [128][131] -> [128][160] pad
            int r = idx / 160, c = idx - r * 160;
            lwh[idx] = (f16)(c < 131 ? lw[r * 131 + c] : 0.f);
        }
        if (idx < 384 * 128) {                        // qkv W, Q rows scaled by QSC
            float v = qw[idx];
            if (idx < 128 * 128) v *= QSC;
            qwh[idx] = (f16)v;
        }
        if (idx < 128 * 128) pwh[idx] = (f16)pw[idx];
        if (idx < 384) qbs[idx] = qb[idx] * (idx < 128 ? QSC : 1.f);
        if (idx < 10240) rpbp[idx] = (idx < 4 * RPBSZ) ? rpb[idx] * LOG2E : 0.f;
    } else {
        int idx = (blockIdx.x - 192) * 256 + threadIdx.x;   // 49152: W2 = qw @ pw
        int i = idx >> 7, k = idx & 127;
        float acc = 0.f;
        for (int j = 0; j < 128; j++) acc += qw[i * 128 + j] * pw[j * 128 + k];
        if (i < 128) acc *= QSC;
        w2h[idx] = (f16)acc;
        if (idx < 384) {
            float b = qb[idx];
            for (int j = 0; j < 128; j++) b += qw[idx * 128 + j] * pb[j];
            b2s[idx] = b * (idx < 128 ? QSC : 1.f);
        }
    }
}

// ---------- fusion GEMM: yh = relu(cat @ lwh^T + lb); grid (352, 2), one 64-n-tile/block ----------
__global__ __launch_bounds__(256) void fusion_gemm(
    const float* __restrict__ x, const float* __restrict__ cond, const float* __restrict__ mask,
    const f16* __restrict__ lwh, const float* __restrict__ lb, f16* __restrict__ yh)
{
    __shared__ __align__(16) f16 Alds[64 * 168];
    const int m0 = blockIdx.x * 64, n0 = blockIdx.y * 64;
    const int tid = threadIdx.x;
    const int w = tid >> 6, lane = tid & 63, quad = lane >> 4, nn = lane & 15;

    {   // stage cat rows (f16)
        int r = tid >> 2, cpart = tid & 3;
        size_t pos = m0 + r;
        *(uint4*)&Alds[r * 168 + 128 + cpart * 8] = make_uint4(0, 0, 0, 0);
        const float* xr = x + pos * 128 + cpart * 32;
        #pragma unroll
        for (int t = 0; t < 4; t++) {
            float4 a = *(const float4*)(xr + t * 8);
            float4 b = *(const float4*)(xr + t * 8 + 4);
            PkU p0, p1, p2, p3;
            p0.h = __builtin_amdgcn_cvt_pkrtz(a.x, a.y);
            p1.h = __builtin_amdgcn_cvt_pkrtz(a.z, a.w);
            p2.h = __builtin_amdgcn_cvt_pkrtz(b.x, b.y);
            p3.h = __builtin_amdgcn_cvt_pkrtz(b.z, b.w);
            *(uint4*)&Alds[r * 168 + cpart * 32 + t * 8] = make_uint4(p0.u, p1.u, p2.u, p3.u);
        }
        if (cpart == 0) {
            Alds[r * 168 + 128] = (f16)cond[pos * 2];
            Alds[r * 168 + 129] = (f16)cond[pos * 2 + 1];
            Alds[r * 168 + 130] = (f16)mask[pos];
        }
    }
    __syncthreads();

    const int oc = n0 + w * 16 + nn;
    f16x8 af[5];
    #pragma unroll
    for (int ks = 0; ks < 5; ks++)
        af[ks] = *(const f16x8*)&lwh[(size_t)oc * 160 + ks * 32 + quad * 8];
    f32x4 acc[4] = {};
    #pragma unroll
    for (int ks = 0; ks < 5; ks++)
        #pragma unroll
        for (int nt = 0; nt < 4; nt++) {
            f16x8 bf = *(const f16x8*)&Alds[(nt * 16 + nn) * 168 + ks * 32 + quad * 8];
            acc[nt] = __builtin_amdgcn_mfma_f32_16x16x32_f16(af[ks], bf, acc[nt], 0, 0, 0);
        }
    float bv[4];
    #pragma unroll
    for (int r = 0; r < 4; r++) bv[r] = lb[n0 + w * 16 + quad * 4 + r];
    #pragma unroll
    for (int nt = 0; nt < 4; nt++) {
        int pos = m0 + nt * 16 + nn;
        PkU p0, p1;
        p0.h = __builtin_amdgcn_cvt_pkrtz(fmaxf(acc[nt][0] + bv[0], 0.f), fmaxf(acc[nt][1] + bv[1], 0.f));
        p1.h = __builtin_amdgcn_cvt_pkrtz(fmaxf(acc[nt][2] + bv[2], 0.f), fmaxf(acc[nt][3] + bv[3], 0.f));
        *(uint2*)&yh[(size_t)pos * 128 + n0 + w * 16 + quad * 4] = make_uint2(p0.u, p1.u);
    }
}

// ---------- qkv GEMM: grid (352, 6), one 64-n-tile/block; Q|K rows stride 256, V transposed ----------
__global__ __launch_bounds__(256) void gemm_qkv(
    const f16* __restrict__ A, const f16* __restrict__ W, const float* __restrict__ bias,
    f16* __restrict__ qkh, f16* __restrict__ vt)
{
    __shared__ __align__(16) f16 Alds[64 * 136];
    const int m0 = blockIdx.x * 64, n0 = blockIdx.y * 64;
    const int tid = threadIdx.x;
    const int w = tid >> 6, lane = tid & 63, quad = lane >> 4, nn = lane & 15;

    for (int i = tid; i < 1024; i += 256) {
        int r = i >> 4, c = i & 15;
        *(uint4*)&Alds[r * 136 + c * 8] = *(const uint4*)&A[(size_t)(m0 + r) * 128 + c * 8];
    }
    __syncthreads();

    const int oc = n0 + w * 16 + nn;
    f16x8 af[4];
    #pragma unroll
    for (int ks = 0; ks < 4; ks++)
        af[ks] = *(const f16x8*)&W[(size_t)oc * 128 + ks * 32 + quad * 8];
    f32x4 acc[4] = {};
    #pragma unroll
    for (int ks = 0; ks < 4; ks++)
        #pragma unroll
        for (int nt = 0; nt < 4; nt++) {
            f16x8 bf = *(const f16x8*)&Alds[(nt * 16 + nn) * 136 + ks * 32 + quad * 8];
            acc[nt] = __builtin_amdgcn_mfma_f32_16x16x32_f16(af[ks], bf, acc[nt], 0, 0, 0);
        }
    float bv[4];
    #pragma unroll
    for (int r = 0; r < 4; r++) bv[r] = bias[n0 + w * 16 + quad * 4 + r];

    if (n0 < 256) {
        #pragma unroll
        for (int nt = 0; nt < 4; nt++) {
            int pos = m0 + nt * 16 + nn;
            PkU p0, p1;
            p0.h = __builtin_amdgcn_cvt_pkrtz(acc[nt][0] + bv[0], acc[nt][1] + bv[1]);
            p1.h = __builtin_amdgcn_cvt_pkrtz(acc[nt][2] + bv[2], acc[nt][3] + bv[3]);
            *(uint2*)&qkh[(size_t)pos * 256 + n0 + w * 16 + quad * 4] = make_uint2(p0.u, p1.u);
        }
    } else {
        #pragma unroll
        for (int nt = 0; nt < 4; nt++) {
            int pos = m0 + nt * 16 + nn;
            #pragma unroll
            for (int r = 0; r < 4; r++) {
                int chg = n0 - 256 + w * 16 + quad * 4 + r;
                vt[(size_t)chg * NPAD + pos] = (f16)(acc[nt][r] + bv[r]);
            }
        }
    }
}

// ---------- final projection: grid (352, 2), fp32 out ----------
__global__ __launch_bounds__(256) void gemm_out(
    const f16* __restrict__ A, const f16* __restrict__ W, const float* __restrict__ bias,
    float* __restrict__ outp)
{
    __shared__ __align__(16) f16 Alds[64 * 136];
    const int m0 = blockIdx.x * 64, n0 = blockIdx.y * 64;
    const int tid = threadIdx.x;
    const int w = tid >> 6, lane = tid & 63, quad = lane >> 4, nn = lane & 15;

    for (int i = tid; i < 1024; i += 256) {
        int r = i >> 4, c = i & 15;
        *(uint4*)&Alds[r * 136 + c * 8] = *(const uint4*)&A[(size_t)(m0 + r) * 128 + c * 8];
    }
    __syncthreads();

    const int oc = n0 + w * 16 + nn;
    f16x8 af[4];
    #pragma unroll
    for (int ks = 0; ks < 4; ks++)
        af[ks] = *(const f16x8*)&W[(size_t)oc * 128 + ks * 32 + quad * 8];
    f32x4 acc[4] = {};
    #pragma unroll
    for (int ks = 0; ks < 4; ks++)
        #pragma unroll
        for (int nt = 0; nt < 4; nt++) {
            f16x8 bf = *(const f16x8*)&Alds[(nt * 16 + nn) * 136 + ks * 32 + quad * 8];
            acc[nt] = __builtin_amdgcn_mfma_f32_16x16x32_f16(af[ks], bf, acc[nt], 0, 0, 0);
        }
    float bv[4];
    #pragma unroll
    for (int r = 0; r < 4; r++) bv[r] = bias[n0 + w * 16 + quad * 4 + r];
    #pragma unroll
    for (int nt = 0; nt < 4; nt++) {
        int pos = m0 + nt * 16 + nn;
        f32x4 vv;
        #pragma unroll
        for (int r = 0; r < 4; r++) vv[r] = acc[nt][r] + bv[r];
        *(f32x4*)&outp[(size_t)pos * 128 + n0 + w * 16 + quad * 4] = vv;
    }
}

// ---------- MFMA neighborhood attention: 8x8 query tile, 2 waves key-split ----------
// rpb+mask folded into S-MFMA accumulator (exp2 domain); l accumulated via MFMA-with-ones
// (reg layout = queries, matches O) -> no VALU sum chain, no epilogue shuffles.
// Wave w handles key rows [w*16, w*16+16); single LDS merge. OOB addrs clamped+masked.
__global__ __launch_bounds__(128) void attn_mfma(
    const f16* __restrict__ qkh,   // [N][256] = Q|K, Q pre-scaled by QSC
    const f16* __restrict__ vt,    // [128][NPAD]
    const float* __restrict__ rpbp,
    f16* __restrict__ ao)          // [N][128]
{
    const int i0 = blockIdx.x * 8;
    const int j0 = blockIdx.y * 8;
    const int h  = blockIdx.z;
    const int tid = threadIdx.x;
    const int w = tid >> 6, lane = tid & 63;
    const int quad = lane >> 4, nn = lane & 15;

    const int ri0 = min(max(i0 - 12, 0), TT - 32);
    const int rj0 = min(max(j0 - 12, 0), PP - WIN) & ~1;

    __shared__ f16 Plds[2][16][40];
    __shared__ __align__(16) float Olds[64][48];   // wave-1 partials: 32 O + 16 lacc

    int qi_[4], si_[4], dbb_[4];
    unsigned cm_[4];
    f16x8 qf[4];
    #pragma unroll
    for (int qs = 0; qs < 4; qs++) {
        int ql = qs * 16 + nn;
        int qi = i0 + (ql >> 3), qj = j0 + (ql & 7);
        int si = min(max(qi - 12, 0), TT - WIN);
        int sj = min(max(qj - 12, 0), PP - WIN);
        qi_[qs] = qi; si_[qs] = si;
        cm_[qs] = 0x1FFFFFFu << (sj - rj0);       // shift <= 7
        dbb_[qs] = rj0 - qj + 24;
        qf[qs] = *(const f16x8*)&qkh[(size_t)(qi * PP + qj) * 256 + h * HD + quad * 8];
    }
    const float* rp_h = rpbp + h * RPBSZ;
    const f16* vbase = vt + (size_t)(h * HD + nn) * NPAD;
    const f16x8 onesv = {(f16)1.f, (f16)1.f, (f16)1.f, (f16)1.f,
                         (f16)1.f, (f16)1.f, (f16)1.f, (f16)1.f};

    f32x4 O[4][2] = {};    // [qset][ch-half]; regs = queries, lane nn = channel
    f32x4 lacc[4] = {};    // regs = queries

    for (int c = w * 16; c < w * 16 + 16; c++) {
        int aa = ri0 + c;                                   // in [0,255]
        const f16* rowK = qkh + (size_t)aa * PP * 256 + 128 + h * HD + quad * 8;
        int b0 = min(rj0 + nn, PP - 1);
        int b1 = min(rj0 + 16 + nn, PP - 1);
        f16x8 kf0 = *(const f16x8*)(rowK + (size_t)b0 * 256);
        f16x8 kf1 = *(const f16x8*)(rowK + (size_t)b1 * 256);
        const f16* vrow = vbase + aa * PP + rj0 + quad * 8;
        f16x8 vf0 = *(const f16x8u*)vrow;
        f16x8 vf1 = *(const f16x8u*)(vrow + (size_t)16 * NPAD);

        #pragma unroll
        for (int qs = 0; qs < 4; qs++) {
            unsigned vm = ((unsigned)(aa - si_[qs]) <= 24u) ? cm_[qs] : 0u;
            const float* rp = rp_h + (aa - qi_[qs] + 24) * RPBW + dbb_[qs];
            f32x4 ra = *(const f32x4u*)(rp + quad * 4);
            f32x4 rb = *(const f32x4u*)(rp + 16 + quad * 4);
            f32x4 za, zb;
            #pragma unroll
            for (int r = 0; r < 4; r++) {
                int kl0 = quad * 4 + r;
                za[r] = ((vm >> kl0) & 1u) ? ra[r] : -1e30f;
                zb[r] = ((vm >> (kl0 + 16)) & 1u) ? rb[r] : -1e30f;
            }
            f32x4 s0 = __builtin_amdgcn_mfma_f32_16x16x32_f16(kf0, qf[qs], za, 0, 0, 0);
            f32x4 s1 = __builtin_amdgcn_mfma_f32_16x16x32_f16(kf1, qf[qs], zb, 0, 0, 0);

            float p[8];
            #pragma unroll
            for (int r = 0; r < 4; r++) {
                p[r]     = EXP2(s0[r]);
                p[r + 4] = EXP2(s1[r]);
            }
            PkU a, b, cc, d;
            a.h  = __builtin_amdgcn_cvt_pkrtz(p[0], p[1]);
            b.h  = __builtin_amdgcn_cvt_pkrtz(p[2], p[3]);
            cc.h = __builtin_amdgcn_cvt_pkrtz(p[4], p[5]);
            d.h  = __builtin_amdgcn_cvt_pkrtz(p[6], p[7]);
            *(unsigned*)&Plds[w][nn][quad * 4]          = a.u;
            *(unsigned*)&Plds[w][nn][quad * 4 + 2]      = b.u;
            *(unsigned*)&Plds[w][nn][16 + quad * 4]     = cc.u;
            *(unsigned*)&Plds[w][nn][16 + quad * 4 + 2] = d.u;
            f16x8 pf = *(const f16x8*)&Plds[w][nn][quad * 8];

            O[qs][0] = __builtin_amdgcn_mfma_f32_16x16x32_f16(pf, vf0, O[qs][0], 0, 0, 0);
            O[qs][1] = __builtin_amdgcn_mfma_f32_16x16x32_f16(pf, vf1, O[qs][1], 0, 0, 0);
            lacc[qs] = __builtin_amdgcn_mfma_f32_16x16x32_f16(pf, onesv, lacc[qs], 0, 0, 0);
        }
    }

    // ---- merge: wave1 stores partials, wave0 adds and finishes ----
    if (w == 1) {
        float* ob = Olds[lane];
        #pragma unroll
        for (int qs = 0; qs < 4; qs++) {
            *(f32x4*)&ob[qs * 12]     = O[qs][0];
            *(f32x4*)&ob[qs * 12 + 4] = O[qs][1];
            *(f32x4*)&ob[qs * 12 + 8] = lacc[qs];
        }
    }
    __syncthreads();
    if (w == 0) {
        const float* ob = Olds[lane];
        #pragma unroll
        for (int qs = 0; qs < 4; qs++) {
            O[qs][0] += *(const f32x4*)&ob[qs * 12];
            O[qs][1] += *(const f32x4*)&ob[qs * 12 + 4];
            lacc[qs] += *(const f32x4*)&ob[qs * 12 + 8];
            #pragma unroll
            for (int r = 0; r < 4; r++) {
                float li = 1.f / lacc[qs][r];
                int ql = qs * 16 + quad * 4 + r;
                int qi = i0 + (ql >> 3), qj = j0 + (ql & 7);
                size_t base = (size_t)(qi * PP + qj) * CC + h * HD;
                ao[base + nn]      = (f16)(O[qs][0][r] * li);
                ao[base + 16 + nn] = (f16)(O[qs][1][r] * li);
            }
        }
    }
}

extern "C" void kernel_launch(void* const* d_in, const int* in_sizes, int n_in,
                              void* d_out, int out_size, void* d_ws, size_t ws_size,
                              hipStream_t stream) {
    (void)in_sizes; (void)n_in; (void)out_size; (void)ws_size;
    const float* x    = (const float*)d_in[0];
    const float* cond = (const float*)d_in[1];
    const float* mask = (const float*)d_in[2];
    const float* lw   = (const float*)d_in[3];
    const float* lb   = (const float*)d_in[4];
    const float* qw   = (const float*)d_in[5];
    const float* qb   = (const float*)d_in[6];
    const float* rpb  = (const float*)d_in[7];
    const float* pw   = (const float*)d_in[8];
    const float* pb   = (const float*)d_in[9];
    float* outp       = (float*)d_out;

    float* ws   = (float*)d_ws;
    float* qbs  = ws;                 // 384
    float* b2s  = qbs + 384;          // 384
    float* rpbp = b2s + 384;          // 10240 padded
    f16* lwh  = (f16*)(rpbp + 10240);             // 128*160
    f16* qwh  = lwh + 20480;                      // 384*128
    f16* pwh  = qwh + 49152;                      // 128*128
    f16* w2h  = pwh + 16384;                      // 384*128
    f16* yh   = w2h + 49152;                      // NN*128
    f16* qkh  = yh + (size_t)NN * 128;            // NN*256 (Q|K)
    f16* vt   = qkh + (size_t)NN * 256;           // 128*NPAD
    f16* ao   = vt + (size_t)128 * NPAD;          // NN*128

    prep<<<384, 256, 0, stream>>>(lw, qw, pw, qb, pb, rpb, lwh, qwh, pwh, w2h, qbs, b2s, rpbp);
    fusion_gemm<<<dim3(352, 2), 256, 0, stream>>>(x, cond, mask, lwh, lb, yh);
    gemm_qkv<<<dim3(352, 6), 256, 0, stream>>>(yh, qwh, qbs, qkh, vt);
    attn_mfma<<<dim3(TT / 8, PP / 8, HEADS), 128, 0, stream>>>(qkh, vt, rpbp, ao);
    gemm_qkv<<<dim3(352, 6), 256, 0, stream>>>(ao, w2h, b2s, qkh, vt);   // fused proj+qkv
    attn_mfma<<<dim3(TT / 8, PP / 8, HEADS), 128, 0, stream>>>(qkh, vt, rpbp, ao);
    gemm_out<<<dim3(352, 2), 256, 0, stream>>>(ao, pwh, pb, outp);
}